// Round 2
// baseline (876.483 us; speedup 1.0000x reference)
//
#include <hip/hip_runtime.h>

// ChannelLatentMixer: out[b, 0:64, :] = z[b]; out[b, 64:128, :] = mean over rows
// with same channel id. B=4096, C=32, N=64, D=128.
#define NB      4096
#define NCH     32
#define ND      8192    // 64*128 floats per z row-block
#define OUTROW  16384   // 2*ND floats per output row-block
#define NSPLIT  8       // row-loop split factor per (channel, chunk)
#define NCHUNK  8       // 8 chunks x 1024 floats = 8192-float row

// ---- kernel 1: build per-channel row lists ---------------------------------
__global__ void build_lists_kernel(const int* __restrict__ ch,
                                   int* __restrict__ counts,
                                   int* __restrict__ lists) {
    int b = blockIdx.x * blockDim.x + threadIdx.x;
    if (b < NB) {
        int c = ch[b];
        int pos = atomicAdd(&counts[c], 1);
        lists[c * NB + pos] = b;
    }
}

// ---- kernel 2: fused copy + reduce + last-block broadcast ------------------
// grid = NCH * NCHUNK * NSPLIT = 2048 blocks of 256 threads (32 waves/CU).
// Block (c, chunk, s) owns column slice [chunk*1024, +1024) of the row and
// rows i = s, s+NSPLIT, ... of channel c's list.
// Phase 1: copy z->out z-half, accumulate partial sum, atomicAdd into sums.
// Phase 2: the LAST of the 8 sibling blocks (done-counter) reads the complete
// channel sum and broadcasts the mean to the aggr-half for ALL rows of c.
__global__ __launch_bounds__(256) void mixer_kernel(
        const float* __restrict__ z,
        const int* __restrict__ counts,
        const int* __restrict__ lists,
        float* __restrict__ sums,
        int* __restrict__ done,
        float* __restrict__ out) {
    const int bid   = blockIdx.x;
    const int s     = bid & (NSPLIT - 1);
    const int chunk = (bid / NSPLIT) & (NCHUNK - 1);
    const int c     = bid / (NSPLIT * NCHUNK);
    const int off   = chunk * 1024 + threadIdx.x * 4;  // float offset in row
    const int cnt   = counts[c];
    const int* __restrict__ lst = lists + c * NB;

    float4 acc = make_float4(0.f, 0.f, 0.f, 0.f);

    // ---- phase 1: copy + partial reduce over this block's row subset ------
    int i = s;
    for (; i + 3 * NSPLIT < cnt; i += 4 * NSPLIT) {
        const int b0 = lst[i];
        const int b1 = lst[i +     NSPLIT];
        const int b2 = lst[i + 2 * NSPLIT];
        const int b3 = lst[i + 3 * NSPLIT];
        const float4 v0 = *(const float4*)(z + (long)b0 * ND + off);
        const float4 v1 = *(const float4*)(z + (long)b1 * ND + off);
        const float4 v2 = *(const float4*)(z + (long)b2 * ND + off);
        const float4 v3 = *(const float4*)(z + (long)b3 * ND + off);
        *(float4*)(out + (long)b0 * OUTROW + off) = v0;
        *(float4*)(out + (long)b1 * OUTROW + off) = v1;
        *(float4*)(out + (long)b2 * OUTROW + off) = v2;
        *(float4*)(out + (long)b3 * OUTROW + off) = v3;
        acc.x += (v0.x + v1.x) + (v2.x + v3.x);
        acc.y += (v0.y + v1.y) + (v2.y + v3.y);
        acc.z += (v0.z + v1.z) + (v2.z + v3.z);
        acc.w += (v0.w + v1.w) + (v2.w + v3.w);
    }
    for (; i < cnt; i += NSPLIT) {
        const int b = lst[i];
        const float4 v = *(const float4*)(z + (long)b * ND + off);
        *(float4*)(out + (long)b * OUTROW + off) = v;
        acc.x += v.x; acc.y += v.y; acc.z += v.z; acc.w += v.w;
    }

    float* dst = sums + (long)c * ND + off;
    atomicAdd(dst + 0, acc.x);
    atomicAdd(dst + 1, acc.y);
    atomicAdd(dst + 2, acc.z);
    atomicAdd(dst + 3, acc.w);

    // ---- release: make this block's sum contributions visible -------------
    __threadfence();
    __syncthreads();

    __shared__ int last;
    if (threadIdx.x == 0) {
        int old = atomicAdd(&done[c * NCHUNK + chunk], 1);
        last = (old == NSPLIT - 1) ? 1 : 0;
    }
    __syncthreads();
    if (!last) return;

    // ---- phase 2 (last sibling block only): finalize + broadcast ----------
    __threadfence();  // acquire: invalidate L1 so sums reads see all atomics
    const float inv = 1.0f / fmaxf((float)cnt, 1.0f);
    float4 m = *(const float4*)(sums + (long)c * ND + off);
    m.x *= inv; m.y *= inv; m.z *= inv; m.w *= inv;

    int j = 0;
    for (; j + 4 <= cnt; j += 4) {
        const int b0 = lst[j + 0];
        const int b1 = lst[j + 1];
        const int b2 = lst[j + 2];
        const int b3 = lst[j + 3];
        *(float4*)(out + (long)b0 * OUTROW + ND + off) = m;
        *(float4*)(out + (long)b1 * OUTROW + ND + off) = m;
        *(float4*)(out + (long)b2 * OUTROW + ND + off) = m;
        *(float4*)(out + (long)b3 * OUTROW + ND + off) = m;
    }
    for (; j < cnt; ++j) {
        const int b = lst[j];
        *(float4*)(out + (long)b * OUTROW + ND + off) = m;
    }
}

extern "C" void kernel_launch(void* const* d_in, const int* in_sizes, int n_in,
                              void* d_out, int out_size, void* d_ws, size_t ws_size,
                              hipStream_t stream) {
    const float* z  = (const float*)d_in[0];
    const int*   ch = (const int*)d_in[1];
    float*       out = (float*)d_out;

    // ws layout:
    //   [0, 128)            counts (32 ints, padded)
    //   [128, 1152)         done flags (NCH*NCHUNK = 256 ints)
    //   [8192, 8192+1MB)    sums (NCH * ND floats)
    //   [8192+1MB, +512KB)  lists (NCH * NB ints)
    int*   counts = (int*)d_ws;
    int*   done   = (int*)((char*)d_ws + 128);
    float* sums   = (float*)((char*)d_ws + 8192);
    int*   lists  = (int*)((char*)d_ws + 8192 + (size_t)NCH * ND * sizeof(float));

    // one memset covers counts + done + sums
    hipMemsetAsync(d_ws, 0, 8192 + (size_t)NCH * ND * sizeof(float), stream);
    build_lists_kernel<<<(NB + 255) / 256, 256, 0, stream>>>(ch, counts, lists);
    mixer_kernel<<<NCH * NCHUNK * NSPLIT, 256, 0, stream>>>(z, counts, lists,
                                                            sums, done, out);
}

// Round 3
// 387.654 us; speedup vs baseline: 2.2610x; 2.2610x over previous
//
#include <hip/hip_runtime.h>

// ChannelLatentMixer: out[b, 0:64, :] = z[b]; out[b, 64:128, :] = mean over rows
// with same channel id. B=4096, C=32, N=64, D=128.
// Structure (all stream-ordered, NO device fences — per-XCD L2 non-coherence
// made the fused R2 version 660us of cache flushing):
//   1. build_lists: per-channel row lists (atomic counts).
//   2. reduce: list-gather partial sums per (c, chunk, s) -> scratch in out's
//      aggr half rows 0..255 (overwritten later by write_kernel).
//   3. finalize: sum 8 partials, scale by 1/cnt -> means table (1 MB in ws).
//   4. write: b-range streaming; reads z (L3-hot) + means (L2-hot), writes
//      BOTH output halves with nontemporal stores (don't evict z from L3).
#define NB      4096
#define NCH     32
#define ND      8192    // 64*128 floats per z row-block
#define OUTROW  16384   // 2*ND floats per output row-block
#define NSPLIT  8       // row-loop split factor for the reduction
#define NCHUNK  8       // 8 chunks x 1024 floats = 8192-float row
#define ROWS_B  16      // rows per block in write_kernel

typedef __attribute__((ext_vector_type(4))) float f4;

// ---- kernel 1: build per-channel row lists ---------------------------------
__global__ void build_lists_kernel(const int* __restrict__ ch,
                                   int* __restrict__ counts,
                                   int* __restrict__ lists) {
    int b = blockIdx.x * blockDim.x + threadIdx.x;
    if (b < NB) {
        int c = ch[b];
        int pos = atomicAdd(&counts[c], 1);
        lists[c * NB + pos] = b;
    }
}

// ---- kernel 2: partial channel sums (no atomics) ---------------------------
// grid = NCH * NCHUNK * NSPLIT = 2048 blocks x 256 thr. Block (c, chunk, s)
// reduces rows i = s, s+8, ... of channel c over column slice chunk.
// Partial (c,s) is a full ND-float row stored in out's aggr-half scratch:
// out[(c*8+s)*OUTROW + ND + off]. Rows 0..255's aggr halves — fully
// overwritten by write_kernel afterwards.
__global__ __launch_bounds__(256) void reduce_kernel(
        const float* __restrict__ z,
        const int* __restrict__ counts,
        const int* __restrict__ lists,
        float* __restrict__ out) {
    const int bid   = blockIdx.x;
    const int s     = bid & (NSPLIT - 1);
    const int chunk = (bid >> 3) & (NCHUNK - 1);
    const int c     = bid >> 6;
    const int off   = chunk * 1024 + threadIdx.x * 4;
    const int cnt   = counts[c];
    const int* __restrict__ lst = lists + c * NB;

    f4 acc = (f4)(0.0f);

    int i = s;
    for (; i + 3 * NSPLIT < cnt; i += 4 * NSPLIT) {
        const int b0 = lst[i];
        const int b1 = lst[i +     NSPLIT];
        const int b2 = lst[i + 2 * NSPLIT];
        const int b3 = lst[i + 3 * NSPLIT];
        const f4 v0 = *(const f4*)(z + (long)b0 * ND + off);
        const f4 v1 = *(const f4*)(z + (long)b1 * ND + off);
        const f4 v2 = *(const f4*)(z + (long)b2 * ND + off);
        const f4 v3 = *(const f4*)(z + (long)b3 * ND + off);
        acc += (v0 + v1) + (v2 + v3);
    }
    for (; i < cnt; i += NSPLIT) {
        const int b = lst[i];
        acc += *(const f4*)(z + (long)b * ND + off);
    }

    // unconditional store: every (c,s) partial slice is initialized even for
    // empty channels (acc = 0), so finalize never reads garbage.
    *(f4*)(out + (long)(c * NSPLIT + s) * OUTROW + ND + off) = acc;
}

// ---- kernel 3: finalize means ----------------------------------------------
// grid = NCH*ND/(256*4) = 256 blocks. One f4 of the means table per thread:
// means[c][d] = (sum_s partial[c][s][d]) / max(cnt, 1).
__global__ __launch_bounds__(256) void finalize_kernel(
        const int* __restrict__ counts,
        const float* __restrict__ out,   // partials live in out scratch
        float* __restrict__ means) {
    const long idx = ((long)blockIdx.x * 256 + threadIdx.x) * 4; // float idx
    const int  c   = (int)(idx >> 13);          // /ND
    const int  d   = (int)(idx & (ND - 1));
    const float* __restrict__ p = out + (long)(c * NSPLIT) * OUTROW + ND + d;

    f4 a = (f4)(0.0f);
#pragma unroll
    for (int s = 0; s < NSPLIT; ++s)
        a += *(const f4*)(p + (long)s * OUTROW);

    const float inv = 1.0f / fmaxf((float)counts[c], 1.0f);
    a *= inv;
    *(f4*)(means + idx) = a;
}

// ---- kernel 4: streaming write of both halves ------------------------------
// grid = (NB/ROWS_B) * NCHUNK = 2048 blocks x 256 thr. Block (g, chunk) owns
// rows [g*16, g*16+16) x column slice chunk. Reads z (L3-hot) and means
// (1 MB, L2-hot); writes out z-half and aggr-half with nontemporal stores.
__global__ __launch_bounds__(256) void write_kernel(
        const float* __restrict__ z,
        const int* __restrict__ ch,
        const float* __restrict__ means,
        float* __restrict__ out) {
    const int bid   = blockIdx.x;
    const int chunk = bid & (NCHUNK - 1);
    const int b0    = (bid >> 3) * ROWS_B;
    const int off   = chunk * 1024 + threadIdx.x * 4;

    int cv[ROWS_B];
#pragma unroll
    for (int r = 0; r < ROWS_B; ++r) cv[r] = ch[b0 + r];

#pragma unroll
    for (int r = 0; r < ROWS_B; r += 4) {
        const f4 v0 = *(const f4*)(z + (long)(b0 + r + 0) * ND + off);
        const f4 v1 = *(const f4*)(z + (long)(b0 + r + 1) * ND + off);
        const f4 v2 = *(const f4*)(z + (long)(b0 + r + 2) * ND + off);
        const f4 v3 = *(const f4*)(z + (long)(b0 + r + 3) * ND + off);
        const f4 m0 = *(const f4*)(means + (long)cv[r + 0] * ND + off);
        const f4 m1 = *(const f4*)(means + (long)cv[r + 1] * ND + off);
        const f4 m2 = *(const f4*)(means + (long)cv[r + 2] * ND + off);
        const f4 m3 = *(const f4*)(means + (long)cv[r + 3] * ND + off);
        __builtin_nontemporal_store(v0, (f4*)(out + (long)(b0 + r + 0) * OUTROW + off));
        __builtin_nontemporal_store(v1, (f4*)(out + (long)(b0 + r + 1) * OUTROW + off));
        __builtin_nontemporal_store(v2, (f4*)(out + (long)(b0 + r + 2) * OUTROW + off));
        __builtin_nontemporal_store(v3, (f4*)(out + (long)(b0 + r + 3) * OUTROW + off));
        __builtin_nontemporal_store(m0, (f4*)(out + (long)(b0 + r + 0) * OUTROW + ND + off));
        __builtin_nontemporal_store(m1, (f4*)(out + (long)(b0 + r + 1) * OUTROW + ND + off));
        __builtin_nontemporal_store(m2, (f4*)(out + (long)(b0 + r + 2) * OUTROW + ND + off));
        __builtin_nontemporal_store(m3, (f4*)(out + (long)(b0 + r + 3) * OUTROW + ND + off));
    }
}

extern "C" void kernel_launch(void* const* d_in, const int* in_sizes, int n_in,
                              void* d_out, int out_size, void* d_ws, size_t ws_size,
                              hipStream_t stream) {
    const float* z  = (const float*)d_in[0];
    const int*   ch = (const int*)d_in[1];
    float*       out = (float*)d_out;

    // ws layout (same ~1.6 MB footprint as the proven R1 version):
    //   [0, 128)                 counts (32 ints, padded)
    //   [8192, 8192+1MB)         means (NCH * ND floats)
    //   [8192+1MB, +512KB)       lists (NCH * NB ints)
    int*   counts = (int*)d_ws;
    float* means  = (float*)((char*)d_ws + 8192);
    int*   lists  = (int*)((char*)d_ws + 8192 + (size_t)NCH * ND * sizeof(float));

    hipMemsetAsync(counts, 0, 128, stream);
    build_lists_kernel<<<(NB + 255) / 256, 256, 0, stream>>>(ch, counts, lists);
    reduce_kernel<<<NCH * NCHUNK * NSPLIT, 256, 0, stream>>>(z, counts, lists, out);
    finalize_kernel<<<NCH * ND / 1024, 256, 0, stream>>>(counts, out, means);
    write_kernel<<<(NB / ROWS_B) * NCHUNK, 256, 0, stream>>>(z, ch, means, out);
}